// Round 6
// baseline (4397.640 us; speedup 1.0000x reference)
//
#include <hip/hip_runtime.h>
#include <hip/hip_fp16.h>
#include <math.h>

#define NN 100000
#define NE 1600000
#define FIN 500
#define HID 256
#define NC 40
#define KIT 5
#define L1P 3.0f
#define GAM 0.25f
#define BET 2.0f
#define OMG 0.75f   // 1 - gamma
#define PAD 64      // fp16 shadow row stride (128 B = one cache line)

// ---------------- build: histograms, scans, permutations ----------------
__global__ void k_hist(const int* __restrict__ s, const int* __restrict__ d, int* cs, int* cd) {
    int e = blockIdx.x * 256 + threadIdx.x;
    if (e < NE) { atomicAdd(&cs[s[e]], 1); atomicAdd(&cd[d[e]], 1); }
}

__global__ void k_scan1(const int* __restrict__ cnt, int* rp, int* bs) {
    __shared__ int sm[1024];
    int i = blockIdx.x * 1024 + threadIdx.x;
    int v = (i < NN) ? cnt[i] : 0;
    sm[threadIdx.x] = v;
    __syncthreads();
    for (int off = 1; off < 1024; off <<= 1) {
        int t = (threadIdx.x >= off) ? sm[threadIdx.x - off] : 0;
        __syncthreads();
        sm[threadIdx.x] += t;
        __syncthreads();
    }
    if (i < NN) rp[i] = sm[threadIdx.x] - v;   // exclusive within block
    if (threadIdx.x == 1023) bs[blockIdx.x] = sm[1023];
}

__global__ void k_scan2(int* bs, int nb) {
    if (threadIdx.x == 0 && blockIdx.x == 0) {
        int run = 0;
        for (int j = 0; j < nb; j++) { int t = bs[j]; bs[j] = run; run += t; }
    }
}

__global__ void k_scan3(int* rp, const int* __restrict__ bs, int total) {
    int i = blockIdx.x * 1024 + threadIdx.x;
    if (i < NN) rp[i] += bs[blockIdx.x];
    if (i == 0) rp[NN] = total;
}

__global__ void k_dis(const int* __restrict__ cs, const int* __restrict__ cd, float* __restrict__ dis) {
    int n = blockIdx.x * 256 + threadIdx.x;
    if (n < NN) dis[n] = rsqrtf((float)(cs[n] + cd[n]) + 1.0f);
}

// src-sorted positions i: sa,sb = endpoints, pd = matching dst-sorted position.
// dst-sorted positions j: da = src endpoint (for ynew's dst-side neighbor gather).
__global__ void k_fillp(const int* __restrict__ s, const int* __restrict__ d,
                        const int* __restrict__ rps, const int* __restrict__ rpd,
                        int* curs, int* curd,
                        int* sa, int* sb, int* pd, int* da) {
    int e = blockIdx.x * 256 + threadIdx.x;
    if (e < NE) {
        int a = s[e], b = d[e];
        int i = rps[a] + atomicAdd(&curs[a], 1);
        int j = rpd[b] + atomicAdd(&curd[b], 1);
        sa[i] = a; sb[i] = b; pd[i] = j; da[j] = a;
    }
}

// ---------------- MLP ----------------
// h1 = relu(x @ W1); fp32 tiled GEMM, 128x128 tile, BK=8, 8x8 microtile
__global__ __launch_bounds__(256) void k_gemm1(const float* __restrict__ X,
                                               const float* __restrict__ W1,
                                               float* __restrict__ H1) {
    __shared__ float As[8][128];
    __shared__ float Bs[8][128];
    const int t = threadIdx.x;
    const int rblk = blockIdx.x * 128;
    const int cblk = blockIdx.y * 128;
    const int tx = t & 15, ty = t >> 4;
    const int lar = t >> 1, lak = (t & 1) * 4;
    const int lbk = t >> 5, lbc = (t & 31) * 4;
    float acc[8][8];
    #pragma unroll
    for (int i = 0; i < 8; i++)
        #pragma unroll
        for (int j = 0; j < 8; j++) acc[i][j] = 0.f;

    for (int k0 = 0; k0 < FIN; k0 += 8) {
        float4 av = make_float4(0.f, 0.f, 0.f, 0.f);
        int row = rblk + lar;
        if (row < NN) {
            if (k0 + lak + 4 <= FIN) {
                av = *(const float4*)(X + (size_t)row * FIN + k0 + lak);
            } else {
                float tv[4] = {0.f, 0.f, 0.f, 0.f};
                #pragma unroll
                for (int j = 0; j < 4; j++)
                    if (k0 + lak + j < FIN) tv[j] = X[(size_t)row * FIN + k0 + lak + j];
                av = make_float4(tv[0], tv[1], tv[2], tv[3]);
            }
        }
        As[lak + 0][lar] = av.x; As[lak + 1][lar] = av.y;
        As[lak + 2][lar] = av.z; As[lak + 3][lar] = av.w;

        float4 bv = make_float4(0.f, 0.f, 0.f, 0.f);
        if (k0 + lbk < FIN) bv = *(const float4*)(W1 + (size_t)(k0 + lbk) * HID + cblk + lbc);
        *(float4*)&Bs[lbk][lbc] = bv;
        __syncthreads();

        #pragma unroll
        for (int kk = 0; kk < 8; kk++) {
            float aF[8], bF[8];
            *(float4*)&aF[0] = *(const float4*)&As[kk][ty * 4];
            *(float4*)&aF[4] = *(const float4*)&As[kk][64 + ty * 4];
            *(float4*)&bF[0] = *(const float4*)&Bs[kk][tx * 4];
            *(float4*)&bF[4] = *(const float4*)&Bs[kk][64 + tx * 4];
            #pragma unroll
            for (int i = 0; i < 8; i++)
                #pragma unroll
                for (int j = 0; j < 8; j++)
                    acc[i][j] = fmaf(aF[i], bF[j], acc[i][j]);
        }
        __syncthreads();
    }

    #pragma unroll
    for (int i = 0; i < 8; i++) {
        int row = rblk + ((i < 4) ? (ty * 4 + i) : (64 + ty * 4 + (i - 4)));
        if (row < NN) {
            float4 v0, v1;
            v0.x = fmaxf(acc[i][0], 0.f); v0.y = fmaxf(acc[i][1], 0.f);
            v0.z = fmaxf(acc[i][2], 0.f); v0.w = fmaxf(acc[i][3], 0.f);
            v1.x = fmaxf(acc[i][4], 0.f); v1.y = fmaxf(acc[i][5], 0.f);
            v1.z = fmaxf(acc[i][6], 0.f); v1.w = fmaxf(acc[i][7], 0.f);
            *(float4*)(H1 + (size_t)row * HID + cblk + tx * 4) = v0;
            *(float4*)(H1 + (size_t)row * HID + cblk + 64 + tx * 4) = v1;
        }
    }
}

// hh = h1 @ W2 ; xg = dis*hh (fp16 shadow). Wave per node, lanes = classes.
__global__ __launch_bounds__(256) void k_gemm2(const float* __restrict__ H1,
                                               const float* __restrict__ W2,
                                               const float* __restrict__ dis,
                                               float* __restrict__ hh, __half* __restrict__ xg) {
    __shared__ float w2s[HID * NC];   // 40 KB
    for (int i = threadIdx.x; i < HID * NC; i += 256) w2s[i] = W2[i];
    __syncthreads();
    int wave = threadIdx.x >> 6, lane = threadIdx.x & 63;
    int n = blockIdx.x * 4 + wave;
    if (n >= NN) return;
    if (lane < NC) {
        const float* hr = H1 + (size_t)n * HID;
        float acc = 0.f;
        #pragma unroll 4
        for (int k = 0; k < HID; k += 4) {
            float4 h4 = *(const float4*)(hr + k);
            acc = fmaf(h4.x, w2s[(k + 0) * NC + lane], acc);
            acc = fmaf(h4.y, w2s[(k + 1) * NC + lane], acc);
            acc = fmaf(h4.z, w2s[(k + 2) * NC + lane], acc);
            acc = fmaf(h4.w, w2s[(k + 3) * NC + lane], acc);
        }
        hh[(size_t)n * NC + lane] = acc;
        xg[(size_t)n * PAD + lane] = __float2half_rn(dis[n] * acc);
    }
}

// ---------------- iteration kernels ----------------
// y = gamma*hh + omega*dn*(self + sum_src-nbrs xg[sb] + sum_dst-nbrs xg[da]);
// xbs = dn*(y - gamma*dn*S_prev) fp16 shadow. Wave per node.
__global__ __launch_bounds__(256) void k_ynew(const int* __restrict__ rps, const int* __restrict__ rpd,
                                              const int* __restrict__ sb, const int* __restrict__ da,
                                              const float* __restrict__ dis, const float* __restrict__ hh,
                                              const float* __restrict__ S, const __half* __restrict__ xg,
                                              float* __restrict__ y, __half* __restrict__ xbs) {
    int wave = threadIdx.x >> 6, lane = threadIdx.x & 63;
    int n = blockIdx.x * 4 + wave;
    if (n >= NN) return;
    if (lane < NC) {
        size_t base = (size_t)n * NC + lane;
        float dn = dis[n];
        float acc = __half2float(xg[(size_t)n * PAD + lane]);   // self term dn*xc
        int p = rps[n], e0 = rps[n + 1];
        for (; p + 3 < e0; p += 4) {
            int c0 = sb[p], c1 = sb[p + 1], c2 = sb[p + 2], c3 = sb[p + 3];
            float v0 = __half2float(xg[(size_t)c0 * PAD + lane]);
            float v1 = __half2float(xg[(size_t)c1 * PAD + lane]);
            float v2 = __half2float(xg[(size_t)c2 * PAD + lane]);
            float v3 = __half2float(xg[(size_t)c3 * PAD + lane]);
            acc += (v0 + v1) + (v2 + v3);
        }
        for (; p < e0; p++)
            acc += __half2float(xg[(size_t)sb[p] * PAD + lane]);
        p = rpd[n]; e0 = rpd[n + 1];
        for (; p + 3 < e0; p += 4) {
            int c0 = da[p], c1 = da[p + 1], c2 = da[p + 2], c3 = da[p + 3];
            float v0 = __half2float(xg[(size_t)c0 * PAD + lane]);
            float v1 = __half2float(xg[(size_t)c1 * PAD + lane]);
            float v2 = __half2float(xg[(size_t)c2 * PAD + lane]);
            float v3 = __half2float(xg[(size_t)c3 * PAD + lane]);
            acc += (v0 + v1) + (v2 + v3);
        }
        for (; p < e0; p++)
            acc += __half2float(xg[(size_t)da[p] * PAD + lane]);
        float yv = GAM * hh[base] + OMG * dn * acc;
        y[base] = yv;
        xbs[(size_t)n * PAD + lane] = __float2half_rn(dn * (yv - GAM * dn * S[base]));
    }
}

// z = prox_L21(z + beta*(xbs[a]-xbs[b])); wave per src-position; contiguous zs, scatter row to zd.
__global__ __launch_bounds__(256) void k_zup(const int* __restrict__ sa, const int* __restrict__ sb,
                                             const int* __restrict__ pd, const __half* __restrict__ xbs,
                                             __half* __restrict__ zs, __half* __restrict__ zd, int use_z) {
    int i = (blockIdx.x * 256 + threadIdx.x) >> 6;
    int lane = threadIdx.x & 63;
    if (i >= NE) return;
    int a = sa[i], b = sb[i], j = pd[i];   // wave-uniform
    float zb = 0.f;
    if (lane < NC) {
        float ia = __half2float(xbs[(size_t)a * PAD + lane]);
        float ib = __half2float(xbs[(size_t)b * PAD + lane]);
        float zv = use_z ? __half2float(zs[(size_t)i * NC + lane]) : 0.f;
        zb = zv + BET * (ia - ib);
    }
    float n2 = zb * zb;
    #pragma unroll
    for (int off = 1; off < 64; off <<= 1) n2 += __shfl_xor(n2, off);
    float rn = sqrtf(n2);
    float scale = (rn > L1P) ? (L1P / rn) : 1.0f;
    if (lane < NC) {
        __half hv = __float2half_rn(zb * scale);
        zs[(size_t)i * NC + lane] = hv;      // contiguous stream
        zd[(size_t)j * NC + lane] = hv;      // random-row scatter write (no RMW)
    }
}

// S[n] = sum(zs src-range) - sum(zd dst-range)  [both contiguous streams];
// xc = y - gamma*dn*S ; xg = dn*xc shadow ; S stored for next ynew.
__global__ __launch_bounds__(256) void k_scx(const int* __restrict__ rps, const int* __restrict__ rpd,
                                             const __half* __restrict__ zs, const __half* __restrict__ zd,
                                             const float* __restrict__ y, const float* __restrict__ dis,
                                             float* __restrict__ S, float* __restrict__ xc,
                                             __half* __restrict__ xg) {
    int wave = threadIdx.x >> 6, lane = threadIdx.x & 63;
    int n = blockIdx.x * 4 + wave;
    if (n >= NN) return;
    if (lane < NC) {
        float acc = 0.f;
        int p = rps[n], e0 = rps[n + 1];
        for (; p + 3 < e0; p += 4) {
            float v0 = __half2float(zs[(size_t)(p + 0) * NC + lane]);
            float v1 = __half2float(zs[(size_t)(p + 1) * NC + lane]);
            float v2 = __half2float(zs[(size_t)(p + 2) * NC + lane]);
            float v3 = __half2float(zs[(size_t)(p + 3) * NC + lane]);
            acc += (v0 + v1) + (v2 + v3);
        }
        for (; p < e0; p++) acc += __half2float(zs[(size_t)p * NC + lane]);
        p = rpd[n]; e0 = rpd[n + 1];
        for (; p + 3 < e0; p += 4) {
            float v0 = __half2float(zd[(size_t)(p + 0) * NC + lane]);
            float v1 = __half2float(zd[(size_t)(p + 1) * NC + lane]);
            float v2 = __half2float(zd[(size_t)(p + 2) * NC + lane]);
            float v3 = __half2float(zd[(size_t)(p + 3) * NC + lane]);
            acc -= (v0 + v1) + (v2 + v3);
        }
        for (; p < e0; p++) acc -= __half2float(zd[(size_t)p * NC + lane]);
        size_t base = (size_t)n * NC + lane;
        float dn = dis[n];
        float v = y[base] - GAM * dn * acc;
        S[base] = acc;
        xc[base] = v;
        xg[(size_t)n * PAD + lane] = __float2half_rn(dn * v);
    }
}

__global__ __launch_bounds__(256) void k_lsm(const float* __restrict__ xc, float* __restrict__ out) {
    int wave = threadIdx.x >> 6, lane = threadIdx.x & 63;
    int n = blockIdx.x * 4 + wave;
    if (n >= NN) return;
    float v = (lane < NC) ? xc[(size_t)n * NC + lane] : -INFINITY;
    float m = v;
    #pragma unroll
    for (int off = 1; off < 64; off <<= 1) m = fmaxf(m, __shfl_xor(m, off));
    float ex = (lane < NC) ? expf(v - m) : 0.f;
    float ssum = ex;
    #pragma unroll
    for (int off = 1; off < 64; off <<= 1) ssum += __shfl_xor(ssum, off);
    if (lane < NC) out[(size_t)n * NC + lane] = v - m - logf(ssum);
}

// ---------------- launch ----------------
extern "C" void kernel_launch(void* const* d_in, const int* in_sizes, int n_in,
                              void* d_out, int out_size, void* d_ws, size_t ws_size,
                              hipStream_t stream) {
    const float* x  = (const float*)d_in[0];
    const float* W1 = (const float*)d_in[1];
    const float* W2 = (const float*)d_in[2];
    const int* src  = (const int*)d_in[3];
    const int* dst  = (const int*)d_in[4];
    float* out = (float*)d_out;

    char* w = (char*)d_ws;
    auto alloc = [&](size_t bytes) { char* p = w; w += (bytes + 255) & ~(size_t)255; return p; };
    float* dis   = (float*)alloc((size_t)NN * 4);
    int*   cs    = (int*)  alloc((size_t)NN * 4);
    int*   cd    = (int*)  alloc((size_t)NN * 4);
    int*   curs  = (int*)  alloc((size_t)NN * 4);
    int*   curd  = (int*)  alloc((size_t)NN * 4);
    int*   rps   = (int*)  alloc((size_t)(NN + 1) * 4);
    int*   rpd   = (int*)  alloc((size_t)(NN + 1) * 4);
    int*   bs    = (int*)  alloc(1024 * 4);
    int*   sa    = (int*)  alloc((size_t)NE * 4);        // 6.4 MB each
    int*   sb    = (int*)  alloc((size_t)NE * 4);
    int*   pd    = (int*)  alloc((size_t)NE * 4);
    int*   da    = (int*)  alloc((size_t)NE * 4);
    float* hh    = (float*)alloc((size_t)NN * NC * 4);   // 16 MB each
    float* xc    = (float*)alloc((size_t)NN * NC * 4);
    float* yb    = (float*)alloc((size_t)NN * NC * 4);
    float* S     = (float*)alloc((size_t)NN * NC * 4);
    __half* xg   = (__half*)alloc((size_t)NN * PAD * 2); // 12.8 MB
    __half* xbs  = (__half*)alloc((size_t)NN * PAD * 2); // 12.8 MB
    __half* zs   = (__half*)alloc((size_t)NE * NC * 2);  // 128 MB, src-ordered z
    __half* zd   = (__half*)alloc((size_t)NE * NC * 2);  // 128 MB, dst-ordered z
    float* h1    = (float*)zs;  // alias: h1 (102.4 MB) consumed by k_gemm2 before zs first written

    hipMemsetAsync(cs, 0, (size_t)NN * 4, stream);
    hipMemsetAsync(cd, 0, (size_t)NN * 4, stream);
    hipMemsetAsync(curs, 0, (size_t)NN * 4, stream);
    hipMemsetAsync(curd, 0, (size_t)NN * 4, stream);
    k_hist<<<(NE + 255) / 256, 256, 0, stream>>>(src, dst, cs, cd);
    int nb = (NN + 1023) / 1024;
    k_scan1<<<nb, 1024, 0, stream>>>(cs, rps, bs);
    k_scan2<<<1, 64, 0, stream>>>(bs, nb);
    k_scan3<<<nb, 1024, 0, stream>>>(rps, bs, NE);
    k_scan1<<<nb, 1024, 0, stream>>>(cd, rpd, bs);
    k_scan2<<<1, 64, 0, stream>>>(bs, nb);
    k_scan3<<<nb, 1024, 0, stream>>>(rpd, bs, NE);
    k_dis<<<(NN + 255) / 256, 256, 0, stream>>>(cs, cd, dis);
    k_fillp<<<(NE + 255) / 256, 256, 0, stream>>>(src, dst, rps, rpd, curs, curd, sa, sb, pd, da);

    k_gemm1<<<dim3((NN + 127) / 128, HID / 128), 256, 0, stream>>>(x, W1, h1);
    k_gemm2<<<(NN + 3) / 4, 256, 0, stream>>>(h1, W2, dis, hh, xg);

    hipMemsetAsync(S, 0, (size_t)NN * NC * 4, stream);   // S(z=0)=0 for t=0 ynew only
    for (int t = 0; t < KIT; t++) {
        k_ynew<<<(NN + 3) / 4, 256, 0, stream>>>(rps, rpd, sb, da, dis, hh, S, xg, yb, xbs);
        k_zup<<<(NE + 3) / 4, 256, 0, stream>>>(sa, sb, pd, xbs, zs, zd, t > 0 ? 1 : 0);
        k_scx<<<(NN + 3) / 4, 256, 0, stream>>>(rps, rpd, zs, zd, yb, dis, S, xc, xg);
    }
    k_lsm<<<(NN + 3) / 4, 256, 0, stream>>>(xc, out);
}

// Round 7
// 3674.704 us; speedup vs baseline: 1.1967x; 1.1967x over previous
//
#include <hip/hip_runtime.h>
#include <hip/hip_fp16.h>
#include <math.h>

#define NN 100000
#define NE 1600000
#define FIN 500
#define HID 256
#define NC 40
#define NC2 20      // half2/float2 per row
#define KIT 5
#define L1P 3.0f
#define GAM 0.25f
#define BET 2.0f
#define OMG 0.75f   // 1 - gamma
#define PADH2 32    // fp16 shadow row stride in half2 units (128 B rows)

// ---------------- build: histograms, scans, permutations ----------------
__global__ void k_hist(const int* __restrict__ s, const int* __restrict__ d, int* cs, int* cd) {
    int e = blockIdx.x * 256 + threadIdx.x;
    if (e < NE) { atomicAdd(&cs[s[e]], 1); atomicAdd(&cd[d[e]], 1); }
}

__global__ void k_scan1(const int* __restrict__ cnt, int* rp, int* bs) {
    __shared__ int sm[1024];
    int i = blockIdx.x * 1024 + threadIdx.x;
    int v = (i < NN) ? cnt[i] : 0;
    sm[threadIdx.x] = v;
    __syncthreads();
    for (int off = 1; off < 1024; off <<= 1) {
        int t = (threadIdx.x >= off) ? sm[threadIdx.x - off] : 0;
        __syncthreads();
        sm[threadIdx.x] += t;
        __syncthreads();
    }
    if (i < NN) rp[i] = sm[threadIdx.x] - v;
    if (threadIdx.x == 1023) bs[blockIdx.x] = sm[1023];
}

__global__ void k_scan2(int* bs, int nb) {
    if (threadIdx.x == 0 && blockIdx.x == 0) {
        int run = 0;
        for (int j = 0; j < nb; j++) { int t = bs[j]; bs[j] = run; run += t; }
    }
}

__global__ void k_scan3(int* rp, const int* __restrict__ bs, int total) {
    int i = blockIdx.x * 1024 + threadIdx.x;
    if (i < NN) rp[i] += bs[blockIdx.x];
    if (i == 0) rp[NN] = total;
}

__global__ void k_dis(const int* __restrict__ cs, const int* __restrict__ cd, float* __restrict__ dis) {
    int n = blockIdx.x * 256 + threadIdx.x;
    if (n < NN) dis[n] = rsqrtf((float)(cs[n] + cd[n]) + 1.0f);
}

__global__ void k_fillp(const int* __restrict__ s, const int* __restrict__ d,
                        const int* __restrict__ rps, const int* __restrict__ rpd,
                        int* curs, int* curd,
                        int* sa, int* sb, int* pd, int* da) {
    int e = blockIdx.x * 256 + threadIdx.x;
    if (e < NE) {
        int a = s[e], b = d[e];
        int i = rps[a] + atomicAdd(&curs[a], 1);
        int j = rpd[b] + atomicAdd(&curd[b], 1);
        sa[i] = a; sb[i] = b; pd[i] = j; da[j] = a;
    }
}

// ---------------- MLP ----------------
__global__ __launch_bounds__(256) void k_gemm1(const float* __restrict__ X,
                                               const float* __restrict__ W1,
                                               float* __restrict__ H1) {
    __shared__ float As[8][128];
    __shared__ float Bs[8][128];
    const int t = threadIdx.x;
    const int rblk = blockIdx.x * 128;
    const int cblk = blockIdx.y * 128;
    const int tx = t & 15, ty = t >> 4;
    const int lar = t >> 1, lak = (t & 1) * 4;
    const int lbk = t >> 5, lbc = (t & 31) * 4;
    float acc[8][8];
    #pragma unroll
    for (int i = 0; i < 8; i++)
        #pragma unroll
        for (int j = 0; j < 8; j++) acc[i][j] = 0.f;

    for (int k0 = 0; k0 < FIN; k0 += 8) {
        float4 av = make_float4(0.f, 0.f, 0.f, 0.f);
        int row = rblk + lar;
        if (row < NN) {
            if (k0 + lak + 4 <= FIN) {
                av = *(const float4*)(X + (size_t)row * FIN + k0 + lak);
            } else {
                float tv[4] = {0.f, 0.f, 0.f, 0.f};
                #pragma unroll
                for (int j = 0; j < 4; j++)
                    if (k0 + lak + j < FIN) tv[j] = X[(size_t)row * FIN + k0 + lak + j];
                av = make_float4(tv[0], tv[1], tv[2], tv[3]);
            }
        }
        As[lak + 0][lar] = av.x; As[lak + 1][lar] = av.y;
        As[lak + 2][lar] = av.z; As[lak + 3][lar] = av.w;

        float4 bv = make_float4(0.f, 0.f, 0.f, 0.f);
        if (k0 + lbk < FIN) bv = *(const float4*)(W1 + (size_t)(k0 + lbk) * HID + cblk + lbc);
        *(float4*)&Bs[lbk][lbc] = bv;
        __syncthreads();

        #pragma unroll
        for (int kk = 0; kk < 8; kk++) {
            float aF[8], bF[8];
            *(float4*)&aF[0] = *(const float4*)&As[kk][ty * 4];
            *(float4*)&aF[4] = *(const float4*)&As[kk][64 + ty * 4];
            *(float4*)&bF[0] = *(const float4*)&Bs[kk][tx * 4];
            *(float4*)&bF[4] = *(const float4*)&Bs[kk][64 + tx * 4];
            #pragma unroll
            for (int i = 0; i < 8; i++)
                #pragma unroll
                for (int j = 0; j < 8; j++)
                    acc[i][j] = fmaf(aF[i], bF[j], acc[i][j]);
        }
        __syncthreads();
    }

    #pragma unroll
    for (int i = 0; i < 8; i++) {
        int row = rblk + ((i < 4) ? (ty * 4 + i) : (64 + ty * 4 + (i - 4)));
        if (row < NN) {
            float4 v0, v1;
            v0.x = fmaxf(acc[i][0], 0.f); v0.y = fmaxf(acc[i][1], 0.f);
            v0.z = fmaxf(acc[i][2], 0.f); v0.w = fmaxf(acc[i][3], 0.f);
            v1.x = fmaxf(acc[i][4], 0.f); v1.y = fmaxf(acc[i][5], 0.f);
            v1.z = fmaxf(acc[i][6], 0.f); v1.w = fmaxf(acc[i][7], 0.f);
            *(float4*)(H1 + (size_t)row * HID + cblk + tx * 4) = v0;
            *(float4*)(H1 + (size_t)row * HID + cblk + 64 + tx * 4) = v1;
        }
    }
}

// hh = h1 @ W2 ; xg = dis*hh (fp16 shadow). Wave per node, lanes = classes.
__global__ __launch_bounds__(256) void k_gemm2(const float* __restrict__ H1,
                                               const float* __restrict__ W2,
                                               const float* __restrict__ dis,
                                               float* __restrict__ hh, __half2* __restrict__ xg2) {
    __shared__ float w2s[HID * NC];   // 40 KB
    for (int i = threadIdx.x; i < HID * NC; i += 256) w2s[i] = W2[i];
    __syncthreads();
    int wave = threadIdx.x >> 6, lane = threadIdx.x & 63;
    int n = blockIdx.x * 4 + wave;
    if (n >= NN) return;
    if (lane < NC) {
        const float* hr = H1 + (size_t)n * HID;
        float acc = 0.f;
        #pragma unroll 4
        for (int k = 0; k < HID; k += 4) {
            float4 h4 = *(const float4*)(hr + k);
            acc = fmaf(h4.x, w2s[(k + 0) * NC + lane], acc);
            acc = fmaf(h4.y, w2s[(k + 1) * NC + lane], acc);
            acc = fmaf(h4.z, w2s[(k + 2) * NC + lane], acc);
            acc = fmaf(h4.w, w2s[(k + 3) * NC + lane], acc);
        }
        hh[(size_t)n * NC + lane] = acc;
        // scalar fp16 shadow store (xg2 viewed as __half array)
        ((__half*)xg2)[(size_t)n * (2 * PADH2) + lane] = __float2half_rn(dis[n] * acc);
    }
}

// ---------------- iteration kernels (half2, 2-way packed) ----------------
// y = gamma*hh + omega*dn*(self + sum_nbr xg);  xbs = dn*(y - gamma*dn*S_prev)
// Wave per node; two 32-lane groups each take alternate neighbors; lanes 0..19 hold half2 pairs.
__global__ __launch_bounds__(256) void k_ynew(const int* __restrict__ rps, const int* __restrict__ rpd,
                                              const int* __restrict__ sb, const int* __restrict__ da,
                                              const float* __restrict__ dis, const float2* __restrict__ hh2,
                                              const float2* __restrict__ S2, const __half2* __restrict__ xg2,
                                              float2* __restrict__ y2, __half2* __restrict__ xbs2) {
    int wave = threadIdx.x >> 6, lane = threadIdx.x & 63;
    int g = lane >> 5, sl = lane & 31;
    int n = blockIdx.x * 4 + wave;
    if (n >= NN) return;
    bool act = sl < NC2;
    float accx = 0.f, accy = 0.f;

    int p = rps[n] + g, e0 = rps[n + 1];
    for (; p + 2 < e0; p += 4) {           // this group handles p, p+2 (other group p+1, p+3)
        int c0 = sb[p], c1 = sb[p + 2];
        if (act) {
            float2 v0 = __half22float2(xg2[(size_t)c0 * PADH2 + sl]);
            float2 v1 = __half22float2(xg2[(size_t)c1 * PADH2 + sl]);
            accx += v0.x + v1.x; accy += v0.y + v1.y;
        }
    }
    if (p < e0) {
        int c = sb[p];
        if (act) {
            float2 v = __half22float2(xg2[(size_t)c * PADH2 + sl]);
            accx += v.x; accy += v.y;
        }
    }
    p = rpd[n] + g; e0 = rpd[n + 1];
    for (; p + 2 < e0; p += 4) {
        int c0 = da[p], c1 = da[p + 2];
        if (act) {
            float2 v0 = __half22float2(xg2[(size_t)c0 * PADH2 + sl]);
            float2 v1 = __half22float2(xg2[(size_t)c1 * PADH2 + sl]);
            accx += v0.x + v1.x; accy += v0.y + v1.y;
        }
    }
    if (p < e0) {
        int c = da[p];
        if (act) {
            float2 v = __half22float2(xg2[(size_t)c * PADH2 + sl]);
            accx += v.x; accy += v.y;
        }
    }
    accx += __shfl_xor(accx, 32);          // combine the two groups
    accy += __shfl_xor(accy, 32);
    if (act && g == 0) {
        float2 self = __half22float2(xg2[(size_t)n * PADH2 + sl]);
        accx += self.x; accy += self.y;
        size_t b2 = (size_t)n * NC2 + sl;
        float dn = dis[n];
        float2 h = hh2[b2], Sv = S2[b2];
        float yx = GAM * h.x + OMG * dn * accx;
        float yy = GAM * h.y + OMG * dn * accy;
        y2[b2] = make_float2(yx, yy);
        xbs2[(size_t)n * PADH2 + sl] = __float22half2_rn(
            make_float2(dn * (yx - GAM * dn * Sv.x), dn * (yy - GAM * dn * Sv.y)));
    }
}

// z = prox_L21(z + beta*(xbs[a]-xbs[b])); 2 edges per wave (one per 32-group), half2 lanes.
__global__ __launch_bounds__(256) void k_zup(const int* __restrict__ sa, const int* __restrict__ sb,
                                             const int* __restrict__ pd, const __half2* __restrict__ xbs2,
                                             __half2* __restrict__ zs2, __half2* __restrict__ zd2, int use_z) {
    int wid = (blockIdx.x * 256 + threadIdx.x) >> 6;
    int lane = threadIdx.x & 63;
    int g = lane >> 5, sl = lane & 31;
    long i = (long)wid * 2 + g;            // edge index (src-order position)
    if (i >= NE) return;
    int a = sa[i], b = sb[i], j = pd[i];
    float zx = 0.f, zy = 0.f;
    bool act = sl < NC2;
    if (act) {
        float2 ia = __half22float2(xbs2[(size_t)a * PADH2 + sl]);
        float2 ib = __half22float2(xbs2[(size_t)b * PADH2 + sl]);
        float2 zv = make_float2(0.f, 0.f);
        if (use_z) zv = __half22float2(zs2[(size_t)i * NC2 + sl]);
        zx = zv.x + BET * (ia.x - ib.x);
        zy = zv.y + BET * (ia.y - ib.y);
    }
    float n2 = zx * zx + zy * zy;
    #pragma unroll
    for (int off = 1; off < 32; off <<= 1) n2 += __shfl_xor(n2, off, 32);
    float rn = sqrtf(n2);
    float sc = (rn > L1P) ? (L1P / rn) : 1.0f;
    if (act) {
        __half2 hv = __float22half2_rn(make_float2(zx * sc, zy * sc));
        zs2[(size_t)i * NC2 + sl] = hv;    // contiguous stream
        zd2[(size_t)j * NC2 + sl] = hv;    // scattered row write (no RMW)
    }
}

// S[n] = sum(zs src-range) - sum(zd dst-range); xc = y - gamma*dn*S; xg = dn*xc shadow.
// Wave per node; two 32-groups take alternate rows; half2 lanes.
__global__ __launch_bounds__(256) void k_scx(const int* __restrict__ rps, const int* __restrict__ rpd,
                                             const __half2* __restrict__ zs2, const __half2* __restrict__ zd2,
                                             const float2* __restrict__ y2, const float* __restrict__ dis,
                                             float2* __restrict__ S2, float2* __restrict__ xc2,
                                             __half2* __restrict__ xg2) {
    int wave = threadIdx.x >> 6, lane = threadIdx.x & 63;
    int g = lane >> 5, sl = lane & 31;
    int n = blockIdx.x * 4 + wave;
    if (n >= NN) return;
    bool act = sl < NC2;
    float accx = 0.f, accy = 0.f;

    int p = rps[n] + g, e0 = rps[n + 1];
    for (; p + 2 < e0; p += 4) {
        if (act) {
            float2 v0 = __half22float2(zs2[(size_t)p * NC2 + sl]);
            float2 v1 = __half22float2(zs2[(size_t)(p + 2) * NC2 + sl]);
            accx += v0.x + v1.x; accy += v0.y + v1.y;
        }
    }
    if (p < e0 && act) {
        float2 v = __half22float2(zs2[(size_t)p * NC2 + sl]);
        accx += v.x; accy += v.y;
    }
    p = rpd[n] + g; e0 = rpd[n + 1];
    for (; p + 2 < e0; p += 4) {
        if (act) {
            float2 v0 = __half22float2(zd2[(size_t)p * NC2 + sl]);
            float2 v1 = __half22float2(zd2[(size_t)(p + 2) * NC2 + sl]);
            accx -= v0.x + v1.x; accy -= v0.y + v1.y;
        }
    }
    if (p < e0 && act) {
        float2 v = __half22float2(zd2[(size_t)p * NC2 + sl]);
        accx -= v.x; accy -= v.y;
    }
    accx += __shfl_xor(accx, 32);
    accy += __shfl_xor(accy, 32);
    if (act && g == 0) {
        size_t b2 = (size_t)n * NC2 + sl;
        float dn = dis[n];
        float2 yv = y2[b2];
        float vx = yv.x - GAM * dn * accx;
        float vy = yv.y - GAM * dn * accy;
        S2[b2] = make_float2(accx, accy);
        xc2[b2] = make_float2(vx, vy);
        xg2[(size_t)n * PADH2 + sl] = __float22half2_rn(make_float2(dn * vx, dn * vy));
    }
}

__global__ __launch_bounds__(256) void k_lsm(const float* __restrict__ xc, float* __restrict__ out) {
    int wave = threadIdx.x >> 6, lane = threadIdx.x & 63;
    int n = blockIdx.x * 4 + wave;
    if (n >= NN) return;
    float v = (lane < NC) ? xc[(size_t)n * NC + lane] : -INFINITY;
    float m = v;
    #pragma unroll
    for (int off = 1; off < 64; off <<= 1) m = fmaxf(m, __shfl_xor(m, off));
    float ex = (lane < NC) ? expf(v - m) : 0.f;
    float ssum = ex;
    #pragma unroll
    for (int off = 1; off < 64; off <<= 1) ssum += __shfl_xor(ssum, off);
    if (lane < NC) out[(size_t)n * NC + lane] = v - m - logf(ssum);
}

// ---------------- launch ----------------
extern "C" void kernel_launch(void* const* d_in, const int* in_sizes, int n_in,
                              void* d_out, int out_size, void* d_ws, size_t ws_size,
                              hipStream_t stream) {
    const float* x  = (const float*)d_in[0];
    const float* W1 = (const float*)d_in[1];
    const float* W2 = (const float*)d_in[2];
    const int* src  = (const int*)d_in[3];
    const int* dst  = (const int*)d_in[4];
    float* out = (float*)d_out;

    char* w = (char*)d_ws;
    auto alloc = [&](size_t bytes) { char* p = w; w += (bytes + 255) & ~(size_t)255; return p; };
    float* dis   = (float*)alloc((size_t)NN * 4);
    int*   cs    = (int*)  alloc((size_t)NN * 4);
    int*   cd    = (int*)  alloc((size_t)NN * 4);
    int*   curs  = (int*)  alloc((size_t)NN * 4);
    int*   curd  = (int*)  alloc((size_t)NN * 4);
    int*   rps   = (int*)  alloc((size_t)(NN + 1) * 4);
    int*   rpd   = (int*)  alloc((size_t)(NN + 1) * 4);
    int*   bs    = (int*)  alloc(1024 * 4);
    int*   sa    = (int*)  alloc((size_t)NE * 4);
    int*   sb    = (int*)  alloc((size_t)NE * 4);
    int*   pd    = (int*)  alloc((size_t)NE * 4);
    int*   da    = (int*)  alloc((size_t)NE * 4);
    float* hh    = (float*)alloc((size_t)NN * NC * 4);
    float* xc    = (float*)alloc((size_t)NN * NC * 4);
    float* yb    = (float*)alloc((size_t)NN * NC * 4);
    float* S     = (float*)alloc((size_t)NN * NC * 4);
    __half2* xg  = (__half2*)alloc((size_t)NN * PADH2 * 4);
    __half2* xbs = (__half2*)alloc((size_t)NN * PADH2 * 4);
    __half2* zs  = (__half2*)alloc((size_t)NE * NC2 * 4);  // 128 MB
    __half2* zd  = (__half2*)alloc((size_t)NE * NC2 * 4);  // 128 MB
    float* h1    = (float*)zs;  // alias: h1 consumed by k_gemm2 before zs first written

    hipMemsetAsync(cs, 0, (size_t)NN * 4, stream);
    hipMemsetAsync(cd, 0, (size_t)NN * 4, stream);
    hipMemsetAsync(curs, 0, (size_t)NN * 4, stream);
    hipMemsetAsync(curd, 0, (size_t)NN * 4, stream);
    k_hist<<<(NE + 255) / 256, 256, 0, stream>>>(src, dst, cs, cd);
    int nb = (NN + 1023) / 1024;
    k_scan1<<<nb, 1024, 0, stream>>>(cs, rps, bs);
    k_scan2<<<1, 64, 0, stream>>>(bs, nb);
    k_scan3<<<nb, 1024, 0, stream>>>(rps, bs, NE);
    k_scan1<<<nb, 1024, 0, stream>>>(cd, rpd, bs);
    k_scan2<<<1, 64, 0, stream>>>(bs, nb);
    k_scan3<<<nb, 1024, 0, stream>>>(rpd, bs, NE);
    k_dis<<<(NN + 255) / 256, 256, 0, stream>>>(cs, cd, dis);
    k_fillp<<<(NE + 255) / 256, 256, 0, stream>>>(src, dst, rps, rpd, curs, curd, sa, sb, pd, da);

    k_gemm1<<<dim3((NN + 127) / 128, HID / 128), 256, 0, stream>>>(x, W1, h1);
    k_gemm2<<<(NN + 3) / 4, 256, 0, stream>>>(h1, W2, dis, hh, xg);

    hipMemsetAsync(S, 0, (size_t)NN * NC * 4, stream);   // S(z=0)=0 for t=0 ynew
    int zblocks = (int)(((size_t)NE / 2 + 3) / 4);       // 2 edges/wave, 4 waves/block
    for (int t = 0; t < KIT; t++) {
        k_ynew<<<(NN + 3) / 4, 256, 0, stream>>>(rps, rpd, sb, da, dis, (const float2*)hh,
                                                 (const float2*)S, xg, (float2*)yb, xbs);
        k_zup<<<zblocks, 256, 0, stream>>>(sa, sb, pd, xbs, zs, zd, t > 0 ? 1 : 0);
        k_scx<<<(NN + 3) / 4, 256, 0, stream>>>(rps, rpd, zs, zd, (const float2*)yb, dis,
                                                (float2*)S, (float2*)xc, xg);
    }
    k_lsm<<<(NN + 3) / 4, 256, 0, stream>>>(xc, out);
}

// Round 10
// 3612.452 us; speedup vs baseline: 1.2174x; 1.0172x over previous
//
#include <hip/hip_runtime.h>
#include <hip/hip_fp16.h>
#include <math.h>

#define NN 100000
#define NE 1600000
#define FIN 500
#define FINP 512    // FIN padded for pre-split W1
#define HID 256
#define NC 40
#define NC2 20      // half2/float2 per row
#define KIT 5
#define L1P 3.0f
#define GAM 0.25f
#define BET 2.0f
#define OMG 0.75f   // 1 - gamma
#define PADH2 32    // fp16 shadow row stride in half2 units (128 B rows)

typedef short bf16x8 __attribute__((ext_vector_type(8)));
typedef unsigned short us8 __attribute__((ext_vector_type(8)));
typedef float f32x4 __attribute__((ext_vector_type(4)));

// split fp32 into bf16 hi (truncate) + bf16 lo (round residual)
__device__ inline void split_bf16(float x, unsigned short& hi, unsigned short& lo) {
    unsigned u = __float_as_uint(x);
    hi = (unsigned short)(u >> 16);
    float r = x - __uint_as_float(u & 0xFFFF0000u);
    unsigned ur = __float_as_uint(r);
    ur += 0x8000u + ((ur >> 16) & 1u);   // rn-even to bf16
    lo = (unsigned short)(ur >> 16);
}

// ---------------- build: histograms, scans, permutations ----------------
__global__ void k_hist(const int* __restrict__ s, const int* __restrict__ d, int* cs, int* cd) {
    int e = blockIdx.x * 256 + threadIdx.x;
    if (e < NE) { atomicAdd(&cs[s[e]], 1); atomicAdd(&cd[d[e]], 1); }
}

__global__ void k_scan1(const int* __restrict__ cnt, int* rp, int* bs) {
    __shared__ int sm[1024];
    int i = blockIdx.x * 1024 + threadIdx.x;
    int v = (i < NN) ? cnt[i] : 0;
    sm[threadIdx.x] = v;
    __syncthreads();
    for (int off = 1; off < 1024; off <<= 1) {
        int t = (threadIdx.x >= off) ? sm[threadIdx.x - off] : 0;
        __syncthreads();
        sm[threadIdx.x] += t;
        __syncthreads();
    }
    if (i < NN) rp[i] = sm[threadIdx.x] - v;
    if (threadIdx.x == 1023) bs[blockIdx.x] = sm[1023];
}

__global__ void k_scan2(int* bs, int nb) {
    if (threadIdx.x == 0 && blockIdx.x == 0) {
        int run = 0;
        for (int j = 0; j < nb; j++) { int t = bs[j]; bs[j] = run; run += t; }
    }
}

__global__ void k_scan3(int* rp, const int* __restrict__ bs, int total) {
    int i = blockIdx.x * 1024 + threadIdx.x;
    if (i < NN) rp[i] += bs[blockIdx.x];
    if (i == 0) rp[NN] = total;
}

__global__ void k_dis(const int* __restrict__ cs, const int* __restrict__ cd, float* __restrict__ dis) {
    int n = blockIdx.x * 256 + threadIdx.x;
    if (n < NN) dis[n] = rsqrtf((float)(cs[n] + cd[n]) + 1.0f);
}

__global__ void k_fillp(const int* __restrict__ s, const int* __restrict__ d,
                        const int* __restrict__ rps, const int* __restrict__ rpd,
                        int* curs, int* curd,
                        int* sa, int* sb, int* pd, int* da) {
    int e = blockIdx.x * 256 + threadIdx.x;
    if (e < NE) {
        int a = s[e], b = d[e];
        int i = rps[a] + atomicAdd(&curs[a], 1);
        int j = rpd[b] + atomicAdd(&curd[b], 1);
        sa[i] = a; sb[i] = b; pd[i] = j; da[j] = a;
    }
}

// ---------------- MLP ----------------
// One-shot: split W1 into transposed bf16 hi/lo, [HID][FINP], zero-padded past FIN.
__global__ void k_splitW(const float* __restrict__ W1, unsigned short* __restrict__ Wh,
                         unsigned short* __restrict__ Wl) {
    int idx = blockIdx.x * 256 + threadIdx.x;   // HID*FINP total
    if (idx >= HID * FINP) return;
    int kk = idx >> 8;        // 0..FINP-1
    int n  = idx & (HID - 1); // 0..255 (coalesced read across n at fixed kk)
    float v = (kk < FIN) ? W1[(size_t)kk * HID + n] : 0.f;
    unsigned short h, l;
    split_bf16(v, h, l);
    Wh[(size_t)n * FINP + kk] = h;
    Wl[(size_t)n * FINP + kk] = l;
}

// h1 = relu(x @ W1) via split-bf16 MFMA: x*W ~= xh*wh + xh*wl + xl*wh (same fp32 acc).
// BM=32 rows x BN=256(=HID) cols per block; BK=32; 4 waves as 2m x 2n.
// B operands come pre-split/transposed from k_splitW (vector us8 loads, no per-block split VALU).
__global__ __launch_bounds__(256) void k_gemm1m(const float* __restrict__ X,
                                                const unsigned short* __restrict__ W1h,
                                                const unsigned short* __restrict__ W1l,
                                                float* __restrict__ H1) {
    __shared__ unsigned short Ah[32][40], Al[32][40];    // 32 rows x BK(+pad)
    __shared__ unsigned short Bh[256][40], Bl[256][40];  // 256 cols x BK(+pad)
    const int t = threadIdx.x;
    const int rblk = blockIdx.x * 32;
    const int lane = t & 63, wv = t >> 6;
    const int mw = (wv >> 1) * 16;        // wave m-strip: 0 or 16
    const int nw = (wv & 1) * 128;        // wave n-strip: 0 or 128
    const int l15 = lane & 15, kg = lane >> 4;

    f32x4 acc[8];
    #pragma unroll
    for (int i = 0; i < 8; i++) acc[i] = (f32x4){0.f, 0.f, 0.f, 0.f};

    const int ar = t >> 3;              // A stage: row 0..31
    const int ak = (t & 7) * 4;         // A stage: k offset 0,4..28
    const int grow = rblk + ar;

    for (int ks = 0; ks < 16; ks++) {
        const int k0 = ks * 32;
        __syncthreads();
        // ---- stage A (32x32 fp32 -> bf16 hi/lo), one float4 per thread ----
        {
            float4 v = make_float4(0.f, 0.f, 0.f, 0.f);
            if (grow < NN && k0 + ak < FIN)
                v = *(const float4*)(X + (size_t)grow * FIN + k0 + ak);
            ushort4 h4, l4;
            split_bf16(v.x, h4.x, l4.x); split_bf16(v.y, h4.y, l4.y);
            split_bf16(v.z, h4.z, l4.z); split_bf16(v.w, h4.w, l4.w);
            *(ushort4*)&Ah[ar][ak] = h4;
            *(ushort4*)&Al[ar][ak] = l4;
        }
        // ---- stage B: thread t owns col t; pre-split vector loads ----
        {
            const size_t wb = (size_t)t * FINP + k0;
            #pragma unroll
            for (int q = 0; q < 4; q++) {
                *(us8*)&Bh[t][q * 8] = *(const us8*)&W1h[wb + q * 8];
                *(us8*)&Bl[t][q * 8] = *(const us8*)&W1l[wb + q * 8];
            }
        }
        __syncthreads();
        // ---- fragments + MFMA ----
        bf16x8 a_h = *(const bf16x8*)&Ah[mw + l15][kg * 8];
        bf16x8 a_l = *(const bf16x8*)&Al[mw + l15][kg * 8];
        #pragma unroll
        for (int nt = 0; nt < 8; nt++) {
            int n = nw + nt * 16 + l15;
            bf16x8 b_h = *(const bf16x8*)&Bh[n][kg * 8];
            bf16x8 b_l = *(const bf16x8*)&Bl[n][kg * 8];
            acc[nt] = __builtin_amdgcn_mfma_f32_16x16x32_bf16(a_h, b_h, acc[nt], 0, 0, 0);
            acc[nt] = __builtin_amdgcn_mfma_f32_16x16x32_bf16(a_h, b_l, acc[nt], 0, 0, 0);
            acc[nt] = __builtin_amdgcn_mfma_f32_16x16x32_bf16(a_l, b_h, acc[nt], 0, 0, 0);
        }
    }
    // ---- epilogue: D row=(lane>>4)*4+reg, col=lane&15 (m89-verified) ----
    const int orow = rblk + mw + kg * 4;
    #pragma unroll
    for (int reg = 0; reg < 4; reg++) {
        int gr = orow + reg;
        if (gr < NN) {
            #pragma unroll
            for (int nt = 0; nt < 8; nt++)
                H1[(size_t)gr * HID + nw + nt * 16 + l15] = fmaxf(acc[nt][reg], 0.f);
        }
    }
}

// hh = h1 @ W2 ; xg = dis*hh (fp16 shadow). Wave per node, lanes = classes.
__global__ __launch_bounds__(256) void k_gemm2(const float* __restrict__ H1,
                                               const float* __restrict__ W2,
                                               const float* __restrict__ dis,
                                               float* __restrict__ hh, __half2* __restrict__ xg2) {
    __shared__ float w2s[HID * NC];   // 40 KB
    for (int i = threadIdx.x; i < HID * NC; i += 256) w2s[i] = W2[i];
    __syncthreads();
    int wave = threadIdx.x >> 6, lane = threadIdx.x & 63;
    int n = blockIdx.x * 4 + wave;
    if (n >= NN) return;
    if (lane < NC) {
        const float* hr = H1 + (size_t)n * HID;
        float acc = 0.f;
        #pragma unroll 4
        for (int k = 0; k < HID; k += 4) {
            float4 h4 = *(const float4*)(hr + k);
            acc = fmaf(h4.x, w2s[(k + 0) * NC + lane], acc);
            acc = fmaf(h4.y, w2s[(k + 1) * NC + lane], acc);
            acc = fmaf(h4.z, w2s[(k + 2) * NC + lane], acc);
            acc = fmaf(h4.w, w2s[(k + 3) * NC + lane], acc);
        }
        hh[(size_t)n * NC + lane] = acc;
        ((__half*)xg2)[(size_t)n * (2 * PADH2) + lane] = __float2half_rn(dis[n] * acc);
    }
}

// ---------------- iteration kernels (half2, 2-way packed) ----------------
__global__ __launch_bounds__(256) void k_ynew(const int* __restrict__ rps, const int* __restrict__ rpd,
                                              const int* __restrict__ sb, const int* __restrict__ da,
                                              const float* __restrict__ dis, const float2* __restrict__ hh2,
                                              const float2* __restrict__ S2, const __half2* __restrict__ xg2,
                                              float2* __restrict__ y2, __half2* __restrict__ xbs2) {
    int wave = threadIdx.x >> 6, lane = threadIdx.x & 63;
    int g = lane >> 5, sl = lane & 31;
    int n = blockIdx.x * 4 + wave;
    if (n >= NN) return;
    bool act = sl < NC2;
    float accx = 0.f, accy = 0.f;

    int p = rps[n] + g, e0 = rps[n + 1];
    for (; p + 2 < e0; p += 4) {
        int c0 = sb[p], c1 = sb[p + 2];
        if (act) {
            float2 v0 = __half22float2(xg2[(size_t)c0 * PADH2 + sl]);
            float2 v1 = __half22float2(xg2[(size_t)c1 * PADH2 + sl]);
            accx += v0.x + v1.x; accy += v0.y + v1.y;
        }
    }
    if (p < e0) {
        int c = sb[p];
        if (act) {
            float2 v = __half22float2(xg2[(size_t)c * PADH2 + sl]);
            accx += v.x; accy += v.y;
        }
    }
    p = rpd[n] + g; e0 = rpd[n + 1];
    for (; p + 2 < e0; p += 4) {
        int c0 = da[p], c1 = da[p + 2];
        if (act) {
            float2 v0 = __half22float2(xg2[(size_t)c0 * PADH2 + sl]);
            float2 v1 = __half22float2(xg2[(size_t)c1 * PADH2 + sl]);
            accx += v0.x + v1.x; accy += v0.y + v1.y;
        }
    }
    if (p < e0) {
        int c = da[p];
        if (act) {
            float2 v = __half22float2(xg2[(size_t)c * PADH2 + sl]);
            accx += v.x; accy += v.y;
        }
    }
    accx += __shfl_xor(accx, 32);
    accy += __shfl_xor(accy, 32);
    if (act && g == 0) {
        float2 self = __half22float2(xg2[(size_t)n * PADH2 + sl]);
        accx += self.x; accy += self.y;
        size_t b2 = (size_t)n * NC2 + sl;
        float dn = dis[n];
        float2 h = hh2[b2], Sv = S2[b2];
        float yx = GAM * h.x + OMG * dn * accx;
        float yy = GAM * h.y + OMG * dn * accy;
        y2[b2] = make_float2(yx, yy);
        xbs2[(size_t)n * PADH2 + sl] = __float22half2_rn(
            make_float2(dn * (yx - GAM * dn * Sv.x), dn * (yy - GAM * dn * Sv.y)));
    }
}

__global__ __launch_bounds__(256) void k_zup(const int* __restrict__ sa, const int* __restrict__ sb,
                                             const int* __restrict__ pd, const __half2* __restrict__ xbs2,
                                             __half2* __restrict__ zs2, __half2* __restrict__ zd2, int use_z) {
    int wid = (blockIdx.x * 256 + threadIdx.x) >> 6;
    int lane = threadIdx.x & 63;
    int g = lane >> 5, sl = lane & 31;
    long i = (long)wid * 2 + g;
    if (i >= NE) return;
    int a = sa[i], b = sb[i], j = pd[i];
    float zx = 0.f, zy = 0.f;
    bool act = sl < NC2;
    if (act) {
        float2 ia = __half22float2(xbs2[(size_t)a * PADH2 + sl]);
        float2 ib = __half22float2(xbs2[(size_t)b * PADH2 + sl]);
        float2 zv = make_float2(0.f, 0.f);
        if (use_z) zv = __half22float2(zs2[(size_t)i * NC2 + sl]);
        zx = zv.x + BET * (ia.x - ib.x);
        zy = zv.y + BET * (ia.y - ib.y);
    }
    float n2 = zx * zx + zy * zy;
    #pragma unroll
    for (int off = 1; off < 32; off <<= 1) n2 += __shfl_xor(n2, off, 32);
    float rn = sqrtf(n2);
    float sc = (rn > L1P) ? (L1P / rn) : 1.0f;
    if (act) {
        __half2 hv = __float22half2_rn(make_float2(zx * sc, zy * sc));
        zs2[(size_t)i * NC2 + sl] = hv;
        zd2[(size_t)j * NC2 + sl] = hv;
    }
}

__global__ __launch_bounds__(256) void k_scx(const int* __restrict__ rps, const int* __restrict__ rpd,
                                             const __half2* __restrict__ zs2, const __half2* __restrict__ zd2,
                                             const float2* __restrict__ y2, const float* __restrict__ dis,
                                             float2* __restrict__ S2, float2* __restrict__ xc2,
                                             __half2* __restrict__ xg2) {
    int wave = threadIdx.x >> 6, lane = threadIdx.x & 63;
    int g = lane >> 5, sl = lane & 31;
    int n = blockIdx.x * 4 + wave;
    if (n >= NN) return;
    bool act = sl < NC2;
    float accx = 0.f, accy = 0.f;

    int p = rps[n] + g, e0 = rps[n + 1];
    for (; p + 2 < e0; p += 4) {
        if (act) {
            float2 v0 = __half22float2(zs2[(size_t)p * NC2 + sl]);
            float2 v1 = __half22float2(zs2[(size_t)(p + 2) * NC2 + sl]);
            accx += v0.x + v1.x; accy += v0.y + v1.y;
        }
    }
    if (p < e0 && act) {
        float2 v = __half22float2(zs2[(size_t)p * NC2 + sl]);
        accx += v.x; accy += v.y;
    }
    p = rpd[n] + g; e0 = rpd[n + 1];
    for (; p + 2 < e0; p += 4) {
        if (act) {
            float2 v0 = __half22float2(zd2[(size_t)p * NC2 + sl]);
            float2 v1 = __half22float2(zd2[(size_t)(p + 2) * NC2 + sl]);
            accx -= v0.x + v1.x; accy -= v0.y + v1.y;
        }
    }
    if (p < e0 && act) {
        float2 v = __half22float2(zd2[(size_t)p * NC2 + sl]);
        accx -= v.x; accy -= v.y;
    }
    accx += __shfl_xor(accx, 32);
    accy += __shfl_xor(accy, 32);
    if (act && g == 0) {
        size_t b2 = (size_t)n * NC2 + sl;
        float dn = dis[n];
        float2 yv = y2[b2];
        float vx = yv.x - GAM * dn * accx;
        float vy = yv.y - GAM * dn * accy;
        S2[b2] = make_float2(accx, accy);
        xc2[b2] = make_float2(vx, vy);
        xg2[(size_t)n * PADH2 + sl] = __float22half2_rn(make_float2(dn * vx, dn * vy));
    }
}

__global__ __launch_bounds__(256) void k_lsm(const float* __restrict__ xc, float* __restrict__ out) {
    int wave = threadIdx.x >> 6, lane = threadIdx.x & 63;
    int n = blockIdx.x * 4 + wave;
    if (n >= NN) return;
    float v = (lane < NC) ? xc[(size_t)n * NC + lane] : -INFINITY;
    float m = v;
    #pragma unroll
    for (int off = 1; off < 64; off <<= 1) m = fmaxf(m, __shfl_xor(m, off));
    float ex = (lane < NC) ? expf(v - m) : 0.f;
    float ssum = ex;
    #pragma unroll
    for (int off = 1; off < 64; off <<= 1) ssum += __shfl_xor(ssum, off);
    if (lane < NC) out[(size_t)n * NC + lane] = v - m - logf(ssum);
}

// ---------------- launch ----------------
extern "C" void kernel_launch(void* const* d_in, const int* in_sizes, int n_in,
                              void* d_out, int out_size, void* d_ws, size_t ws_size,
                              hipStream_t stream) {
    const float* x  = (const float*)d_in[0];
    const float* W1 = (const float*)d_in[1];
    const float* W2 = (const float*)d_in[2];
    const int* src  = (const int*)d_in[3];
    const int* dst  = (const int*)d_in[4];
    float* out = (float*)d_out;

    char* w = (char*)d_ws;
    auto alloc = [&](size_t bytes) { char* p = w; w += (bytes + 255) & ~(size_t)255; return p; };
    float* dis   = (float*)alloc((size_t)NN * 4);
    int*   cs    = (int*)  alloc((size_t)NN * 4);
    int*   cd    = (int*)  alloc((size_t)NN * 4);
    int*   curs  = (int*)  alloc((size_t)NN * 4);
    int*   curd  = (int*)  alloc((size_t)NN * 4);
    int*   rps   = (int*)  alloc((size_t)(NN + 1) * 4);
    int*   rpd   = (int*)  alloc((size_t)(NN + 1) * 4);
    int*   bs    = (int*)  alloc(1024 * 4);
    int*   sa    = (int*)  alloc((size_t)NE * 4);
    int*   sb    = (int*)  alloc((size_t)NE * 4);
    int*   pd    = (int*)  alloc((size_t)NE * 4);
    int*   da    = (int*)  alloc((size_t)NE * 4);
    unsigned short* W1h = (unsigned short*)alloc((size_t)HID * FINP * 2);  // 256 KB
    unsigned short* W1l = (unsigned short*)alloc((size_t)HID * FINP * 2);  // 256 KB
    float* hh    = (float*)alloc((size_t)NN * NC * 4);
    float* xc    = (float*)alloc((size_t)NN * NC * 4);
    float* yb    = (float*)alloc((size_t)NN * NC * 4);
    float* S     = (float*)alloc((size_t)NN * NC * 4);
    __half2* xg  = (__half2*)alloc((size_t)NN * PADH2 * 4);
    __half2* xbs = (__half2*)alloc((size_t)NN * PADH2 * 4);
    __half2* zs  = (__half2*)alloc((size_t)NE * NC2 * 4);  // 128 MB
    __half2* zd  = (__half2*)alloc((size_t)NE * NC2 * 4);  // 128 MB
    float* h1    = (float*)zs;  // alias: h1 consumed by k_gemm2 before zs first written

    hipMemsetAsync(cs, 0, (size_t)NN * 4, stream);
    hipMemsetAsync(cd, 0, (size_t)NN * 4, stream);
    hipMemsetAsync(curs, 0, (size_t)NN * 4, stream);
    hipMemsetAsync(curd, 0, (size_t)NN * 4, stream);
    k_hist<<<(NE + 255) / 256, 256, 0, stream>>>(src, dst, cs, cd);
    int nb = (NN + 1023) / 1024;
    k_scan1<<<nb, 1024, 0, stream>>>(cs, rps, bs);
    k_scan2<<<1, 64, 0, stream>>>(bs, nb);
    k_scan3<<<nb, 1024, 0, stream>>>(rps, bs, NE);
    k_scan1<<<nb, 1024, 0, stream>>>(cd, rpd, bs);
    k_scan2<<<1, 64, 0, stream>>>(bs, nb);
    k_scan3<<<nb, 1024, 0, stream>>>(rpd, bs, NE);
    k_dis<<<(NN + 255) / 256, 256, 0, stream>>>(cs, cd, dis);
    k_fillp<<<(NE + 255) / 256, 256, 0, stream>>>(src, dst, rps, rpd, curs, curd, sa, sb, pd, da);

    k_splitW<<<(HID * FINP + 255) / 256, 256, 0, stream>>>(W1, W1h, W1l);
    k_gemm1m<<<(NN + 31) / 32, 256, 0, stream>>>(x, W1h, W1l, h1);
    k_gemm2<<<(NN + 3) / 4, 256, 0, stream>>>(h1, W2, dis, hh, xg);

    hipMemsetAsync(S, 0, (size_t)NN * NC * 4, stream);   // S(z=0)=0 for t=0 ynew
    int zblocks = (int)(((size_t)NE / 2 + 3) / 4);       // 2 edges/wave, 4 waves/block
    for (int t = 0; t < KIT; t++) {
        k_ynew<<<(NN + 3) / 4, 256, 0, stream>>>(rps, rpd, sb, da, dis, (const float2*)hh,
                                                 (const float2*)S, xg, (float2*)yb, xbs);
        k_zup<<<zblocks, 256, 0, stream>>>(sa, sb, pd, xbs, zs, zd, t > 0 ? 1 : 0);
        k_scx<<<(NN + 3) / 4, 256, 0, stream>>>(rps, rpd, zs, zd, (const float2*)yb, dis,
                                                (float2*)S, (float2*)xc, xg);
    }
    k_lsm<<<(NN + 3) / 4, 256, 0, stream>>>(xc, out);
}

// Round 12
// 3362.271 us; speedup vs baseline: 1.3079x; 1.0744x over previous
//
#include <hip/hip_runtime.h>
#include <hip/hip_fp16.h>
#include <math.h>

#define NN 100000
#define NE 1600000
#define FIN 500
#define FINP 512    // FIN padded for pre-split W1
#define HID 256
#define NC 40
#define NC2 20      // half2/float2 per row
#define KIT 5
#define L1P 3.0f
#define GAM 0.25f
#define BET 2.0f
#define OMG 0.75f   // 1 - gamma
#define PADH2 32    // fp16 shadow row stride in half2 units (128 B rows)

typedef short bf16x8 __attribute__((ext_vector_type(8)));
typedef unsigned short us8 __attribute__((ext_vector_type(8)));
typedef float f32x4 __attribute__((ext_vector_type(4)));

// split fp32 into bf16 hi (truncate) + bf16 lo (round residual)
__device__ inline void split_bf16(float x, unsigned short& hi, unsigned short& lo) {
    unsigned u = __float_as_uint(x);
    hi = (unsigned short)(u >> 16);
    float r = x - __uint_as_float(u & 0xFFFF0000u);
    unsigned ur = __float_as_uint(r);
    ur += 0x8000u + ((ur >> 16) & 1u);   // rn-even to bf16
    lo = (unsigned short)(ur >> 16);
}

// ---------------- build: histograms, scans, permutations ----------------
__global__ void k_hist(const int* __restrict__ s, const int* __restrict__ d, int* cs, int* cd) {
    int e = blockIdx.x * 256 + threadIdx.x;
    if (e < NE) { atomicAdd(&cs[s[e]], 1); atomicAdd(&cd[d[e]], 1); }
}

__global__ void k_scan1(const int* __restrict__ cnt, int* rp, int* bs) {
    __shared__ int sm[1024];
    int i = blockIdx.x * 1024 + threadIdx.x;
    int v = (i < NN) ? cnt[i] : 0;
    sm[threadIdx.x] = v;
    __syncthreads();
    for (int off = 1; off < 1024; off <<= 1) {
        int t = (threadIdx.x >= off) ? sm[threadIdx.x - off] : 0;
        __syncthreads();
        sm[threadIdx.x] += t;
        __syncthreads();
    }
    if (i < NN) rp[i] = sm[threadIdx.x] - v;
    if (threadIdx.x == 1023) bs[blockIdx.x] = sm[1023];
}

__global__ void k_scan2(int* bs, int nb) {
    if (threadIdx.x == 0 && blockIdx.x == 0) {
        int run = 0;
        for (int j = 0; j < nb; j++) { int t = bs[j]; bs[j] = run; run += t; }
    }
}

__global__ void k_scan3(int* rp, const int* __restrict__ bs, int total) {
    int i = blockIdx.x * 1024 + threadIdx.x;
    if (i < NN) rp[i] += bs[blockIdx.x];
    if (i == 0) rp[NN] = total;
}

__global__ void k_dis(const int* __restrict__ cs, const int* __restrict__ cd, float* __restrict__ dis) {
    int n = blockIdx.x * 256 + threadIdx.x;
    if (n < NN) dis[n] = rsqrtf((float)(cs[n] + cd[n]) + 1.0f);
}

__global__ void k_fillp(const int* __restrict__ s, const int* __restrict__ d,
                        const int* __restrict__ rps, const int* __restrict__ rpd,
                        int* curs, int* curd,
                        int* sa, int* sb, int* pd, int* da) {
    int e = blockIdx.x * 256 + threadIdx.x;
    if (e < NE) {
        int a = s[e], b = d[e];
        int i = rps[a] + atomicAdd(&curs[a], 1);
        int j = rpd[b] + atomicAdd(&curd[b], 1);
        sa[i] = a; sb[i] = b; pd[i] = j; da[j] = a;
    }
}

// ---------------- MLP ----------------
// One-shot: split W1 into transposed bf16 hi/lo, [HID][FINP], zero-padded past FIN.
__global__ void k_splitW(const float* __restrict__ W1, unsigned short* __restrict__ Wh,
                         unsigned short* __restrict__ Wl) {
    int idx = blockIdx.x * 256 + threadIdx.x;   // HID*FINP total
    if (idx >= HID * FINP) return;
    int kk = idx >> 8;        // 0..FINP-1
    int n  = idx & (HID - 1); // 0..255 (coalesced read across n at fixed kk)
    float v = (kk < FIN) ? W1[(size_t)kk * HID + n] : 0.f;
    unsigned short h, l;
    split_bf16(v, h, l);
    Wh[(size_t)n * FINP + kk] = h;
    Wl[(size_t)n * FINP + kk] = l;
}

// h1 = relu(x @ W1) via split-bf16 MFMA: x*W ~= xh*wh + xh*wl + xl*wh (same fp32 acc).
// BM=32 x BN=256 x BK=32; 4 waves as 2m x 2n.
// FRAGMENT-MAJOR LDS: every fragment read is 64 lanes x 16 B contiguous (zero conflicts);
// staging writes hit distinct 16 B slots (bank-class = l15%8, 2 lanes/class = free).
__global__ __launch_bounds__(256) void k_gemm1m(const float* __restrict__ X,
                                                const unsigned short* __restrict__ W1h,
                                                const unsigned short* __restrict__ W1l,
                                                float* __restrict__ H1) {
    __shared__ us8 AFh[2][4][16], AFl[2][4][16];          // [mh][kg][l15], 2 KB each
    __shared__ us8 BFh[2][8][4][16], BFl[2][8][4][16];    // [nh][nt][kg][l15], 16 KB each
    const int t = threadIdx.x;
    const int rblk = blockIdx.x * 32;
    const int lane = t & 63, wv = t >> 6;
    const int mh = wv >> 1;               // wave m-half: 0/1 (16 rows each)
    const int nh = wv & 1;                // wave n-half: 0/1 (128 cols each)
    const int l15 = lane & 15, kg = lane >> 4;

    f32x4 acc[8];
    #pragma unroll
    for (int i = 0; i < 8; i++) acc[i] = (f32x4){0.f, 0.f, 0.f, 0.f};

    // A-staging: thread t -> row ar (0..31), half-octet koct (0..7) = 4 floats
    const int ar = t >> 3;
    const int koct = t & 7;
    const int akg = koct >> 1, ahalf = koct & 1;
    const int grow = rblk + ar;
    // B-staging: thread t owns col t
    const int bnh = t >> 7, bnt = (t & 127) >> 4, bl15 = t & 15;

    for (int ks = 0; ks < 16; ks++) {
        const int k0 = ks * 32;
        __syncthreads();
        // ---- stage A: fp32 float4 -> bf16 hi/lo, fragment-major ----
        {
            float4 v = make_float4(0.f, 0.f, 0.f, 0.f);
            if (grow < NN && k0 + koct * 4 < FIN)
                v = *(const float4*)(X + (size_t)grow * FIN + k0 + koct * 4);
            ushort4 h4, l4;
            split_bf16(v.x, h4.x, l4.x); split_bf16(v.y, h4.y, l4.y);
            split_bf16(v.z, h4.z, l4.z); split_bf16(v.w, h4.w, l4.w);
            ((ushort4*)&AFh[ar >> 4][akg][ar & 15])[ahalf] = h4;
            ((ushort4*)&AFl[ar >> 4][akg][ar & 15])[ahalf] = l4;
        }
        // ---- stage B: pre-split vector loads, fragment-major ----
        {
            const size_t wb = (size_t)t * FINP + k0;
            #pragma unroll
            for (int q = 0; q < 4; q++) {
                BFh[bnh][bnt][q][bl15] = *(const us8*)&W1h[wb + q * 8];
                BFl[bnh][bnt][q][bl15] = *(const us8*)&W1l[wb + q * 8];
            }
        }
        __syncthreads();
        // ---- fragments + MFMA (contiguous 1024 B reads per instruction) ----
        bf16x8 a_h = *(const bf16x8*)&AFh[mh][kg][l15];
        bf16x8 a_l = *(const bf16x8*)&AFl[mh][kg][l15];
        #pragma unroll
        for (int nt = 0; nt < 8; nt++) {
            bf16x8 b_h = *(const bf16x8*)&BFh[nh][nt][kg][l15];
            bf16x8 b_l = *(const bf16x8*)&BFl[nh][nt][kg][l15];
            acc[nt] = __builtin_amdgcn_mfma_f32_16x16x32_bf16(a_h, b_h, acc[nt], 0, 0, 0);
            acc[nt] = __builtin_amdgcn_mfma_f32_16x16x32_bf16(a_h, b_l, acc[nt], 0, 0, 0);
            acc[nt] = __builtin_amdgcn_mfma_f32_16x16x32_bf16(a_l, b_h, acc[nt], 0, 0, 0);
        }
    }
    // ---- epilogue: D row=(lane>>4)*4+reg, col=lane&15 (m89-verified, unchanged) ----
    const int orow = rblk + mh * 16 + kg * 4;
    const int nw = nh * 128;
    #pragma unroll
    for (int reg = 0; reg < 4; reg++) {
        int gr = orow + reg;
        if (gr < NN) {
            #pragma unroll
            for (int nt = 0; nt < 8; nt++)
                H1[(size_t)gr * HID + nw + nt * 16 + l15] = fmaxf(acc[nt][reg], 0.f);
        }
    }
}

// hh = h1 @ W2 ; xg = dis*hh (fp16 shadow). Wave per node, lanes = classes.
__global__ __launch_bounds__(256) void k_gemm2(const float* __restrict__ H1,
                                               const float* __restrict__ W2,
                                               const float* __restrict__ dis,
                                               float* __restrict__ hh, __half2* __restrict__ xg2) {
    __shared__ float w2s[HID * NC];   // 40 KB
    for (int i = threadIdx.x; i < HID * NC; i += 256) w2s[i] = W2[i];
    __syncthreads();
    int wave = threadIdx.x >> 6, lane = threadIdx.x & 63;
    int n = blockIdx.x * 4 + wave;
    if (n >= NN) return;
    if (lane < NC) {
        const float* hr = H1 + (size_t)n * HID;
        float acc = 0.f;
        #pragma unroll 4
        for (int k = 0; k < HID; k += 4) {
            float4 h4 = *(const float4*)(hr + k);
            acc = fmaf(h4.x, w2s[(k + 0) * NC + lane], acc);
            acc = fmaf(h4.y, w2s[(k + 1) * NC + lane], acc);
            acc = fmaf(h4.z, w2s[(k + 2) * NC + lane], acc);
            acc = fmaf(h4.w, w2s[(k + 3) * NC + lane], acc);
        }
        hh[(size_t)n * NC + lane] = acc;
        ((__half*)xg2)[(size_t)n * (2 * PADH2) + lane] = __float2half_rn(dis[n] * acc);
    }
}

// ---------------- iteration kernels (half2, 2-way packed, 4-deep ILP) ----------------
__global__ __launch_bounds__(256) void k_ynew(const int* __restrict__ rps, const int* __restrict__ rpd,
                                              const int* __restrict__ sb, const int* __restrict__ da,
                                              const float* __restrict__ dis, const float2* __restrict__ hh2,
                                              const float2* __restrict__ S2, const __half2* __restrict__ xg2,
                                              float2* __restrict__ y2, __half2* __restrict__ xbs2) {
    int wave = threadIdx.x >> 6, lane = threadIdx.x & 63;
    int g = lane >> 5, sl = lane & 31;
    int n = blockIdx.x * 4 + wave;
    if (n >= NN) return;
    bool act = sl < NC2;
    float accx = 0.f, accy = 0.f;

    #pragma unroll
    for (int side = 0; side < 2; side++) {
        const int* __restrict__ idx = side ? da : sb;
        int p = (side ? rpd[n] : rps[n]) + g;
        int e0 = side ? rpd[n + 1] : rps[n + 1];
        for (; p + 6 < e0; p += 8) {               // 4 rows/group in flight
            int c0 = idx[p], c1 = idx[p + 2], c2 = idx[p + 4], c3 = idx[p + 6];
            if (act) {
                float2 v0 = __half22float2(xg2[(size_t)c0 * PADH2 + sl]);
                float2 v1 = __half22float2(xg2[(size_t)c1 * PADH2 + sl]);
                float2 v2 = __half22float2(xg2[(size_t)c2 * PADH2 + sl]);
                float2 v3 = __half22float2(xg2[(size_t)c3 * PADH2 + sl]);
                accx += (v0.x + v1.x) + (v2.x + v3.x);
                accy += (v0.y + v1.y) + (v2.y + v3.y);
            }
        }
        for (; p + 2 < e0; p += 4) {
            int c0 = idx[p], c1 = idx[p + 2];
            if (act) {
                float2 v0 = __half22float2(xg2[(size_t)c0 * PADH2 + sl]);
                float2 v1 = __half22float2(xg2[(size_t)c1 * PADH2 + sl]);
                accx += v0.x + v1.x; accy += v0.y + v1.y;
            }
        }
        if (p < e0) {
            int c = idx[p];
            if (act) {
                float2 v = __half22float2(xg2[(size_t)c * PADH2 + sl]);
                accx += v.x; accy += v.y;
            }
        }
    }
    accx += __shfl_xor(accx, 32);
    accy += __shfl_xor(accy, 32);
    if (act && g == 0) {
        float2 self = __half22float2(xg2[(size_t)n * PADH2 + sl]);
        accx += self.x; accy += self.y;
        size_t b2 = (size_t)n * NC2 + sl;
        float dn = dis[n];
        float2 h = hh2[b2], Sv = S2[b2];
        float yx = GAM * h.x + OMG * dn * accx;
        float yy = GAM * h.y + OMG * dn * accy;
        y2[b2] = make_float2(yx, yy);
        xbs2[(size_t)n * PADH2 + sl] = __float22half2_rn(
            make_float2(dn * (yx - GAM * dn * Sv.x), dn * (yy - GAM * dn * Sv.y)));
    }
}

__global__ __launch_bounds__(256) void k_zup(const int* __restrict__ sa, const int* __restrict__ sb,
                                             const int* __restrict__ pd, const __half2* __restrict__ xbs2,
                                             __half2* __restrict__ zs2, __half2* __restrict__ zd2, int use_z) {
    int wid = (blockIdx.x * 256 + threadIdx.x) >> 6;
    int lane = threadIdx.x & 63;
    int g = lane >> 5, sl = lane & 31;
    long i = (long)wid * 2 + g;
    if (i >= NE) return;
    int a = sa[i], b = sb[i], j = pd[i];
    float zx = 0.f, zy = 0.f;
    bool act = sl < NC2;
    if (act) {
        float2 ia = __half22float2(xbs2[(size_t)a * PADH2 + sl]);
        float2 ib = __half22float2(xbs2[(size_t)b * PADH2 + sl]);
        float2 zv = make_float2(0.f, 0.f);
        if (use_z) zv = __half22float2(zs2[(size_t)i * NC2 + sl]);
        zx = zv.x + BET * (ia.x - ib.x);
        zy = zv.y + BET * (ia.y - ib.y);
    }
    float n2 = zx * zx + zy * zy;
    #pragma unroll
    for (int off = 1; off < 32; off <<= 1) n2 += __shfl_xor(n2, off, 32);
    float rn = sqrtf(n2);
    float sc = (rn > L1P) ? (L1P / rn) : 1.0f;
    if (act) {
        __half2 hv = __float22half2_rn(make_float2(zx * sc, zy * sc));
        zs2[(size_t)i * NC2 + sl] = hv;
        zd2[(size_t)j * NC2 + sl] = hv;
    }
}

__global__ __launch_bounds__(256) void k_scx(const int* __restrict__ rps, const int* __restrict__ rpd,
                                             const __half2* __restrict__ zs2, const __half2* __restrict__ zd2,
                                             const float2* __restrict__ y2, const float* __restrict__ dis,
                                             float2* __restrict__ S2, float2* __restrict__ xc2,
                                             __half2* __restrict__ xg2) {
    int wave = threadIdx.x >> 6, lane = threadIdx.x & 63;
    int g = lane >> 5, sl = lane & 31;
    int n = blockIdx.x * 4 + wave;
    if (n >= NN) return;
    bool act = sl < NC2;
    float accx = 0.f, accy = 0.f;

    int p = rps[n] + g, e0 = rps[n + 1];
    for (; p + 6 < e0; p += 8) {                   // 4 rows/group in flight
        if (act) {
            float2 v0 = __half22float2(zs2[(size_t)(p + 0) * NC2 + sl]);
            float2 v1 = __half22float2(zs2[(size_t)(p + 2) * NC2 + sl]);
            float2 v2 = __half22float2(zs2[(size_t)(p + 4) * NC2 + sl]);
            float2 v3 = __half22float2(zs2[(size_t)(p + 6) * NC2 + sl]);
            accx += (v0.x + v1.x) + (v2.x + v3.x);
            accy += (v0.y + v1.y) + (v2.y + v3.y);
        }
    }
    for (; p + 2 < e0; p += 4) {
        if (act) {
            float2 v0 = __half22float2(zs2[(size_t)(p + 0) * NC2 + sl]);
            float2 v1 = __half22float2(zs2[(size_t)(p + 2) * NC2 + sl]);
            accx += v0.x + v1.x; accy += v0.y + v1.y;
        }
    }
    if (p < e0 && act) {
        float2 v = __half22float2(zs2[(size_t)p * NC2 + sl]);
        accx += v.x; accy += v.y;
    }
    p = rpd[n] + g; e0 = rpd[n + 1];
    for (; p + 6 < e0; p += 8) {
        if (act) {
            float2 v0 = __half22float2(zd2[(size_t)(p + 0) * NC2 + sl]);
            float2 v1 = __half22float2(zd2[(size_t)(p + 2) * NC2 + sl]);
            float2 v2 = __half22float2(zd2[(size_t)(p + 4) * NC2 + sl]);
            float2 v3 = __half22float2(zd2[(size_t)(p + 6) * NC2 + sl]);
            accx -= (v0.x + v1.x) + (v2.x + v3.x);
            accy -= (v0.y + v1.y) + (v2.y + v3.y);
        }
    }
    for (; p + 2 < e0; p += 4) {
        if (act) {
            float2 v0 = __half22float2(zd2[(size_t)(p + 0) * NC2 + sl]);
            float2 v1 = __half22float2(zd2[(size_t)(p + 2) * NC2 + sl]);
            accx -= v0.x + v1.x; accy -= v0.y + v1.y;
        }
    }
    if (p < e0 && act) {
        float2 v = __half22float2(zd2[(size_t)p * NC2 + sl]);
        accx -= v.x; accy -= v.y;
    }
    accx += __shfl_xor(accx, 32);
    accy += __shfl_xor(accy, 32);
    if (act && g == 0) {
        size_t b2 = (size_t)n * NC2 + sl;
        float dn = dis[n];
        float2 yv = y2[b2];
        float vx = yv.x - GAM * dn * accx;
        float vy = yv.y - GAM * dn * accy;
        S2[b2] = make_float2(accx, accy);
        xc2[b2] = make_float2(vx, vy);
        xg2[(size_t)n * PADH2 + sl] = __float22half2_rn(make_float2(dn * vx, dn * vy));
    }
}

__global__ __launch_bounds__(256) void k_lsm(const float* __restrict__ xc, float* __restrict__ out) {
    int wave = threadIdx.x >> 6, lane = threadIdx.x & 63;
    int n = blockIdx.x * 4 + wave;
    if (n >= NN) return;
    float v = (lane < NC) ? xc[(size_t)n * NC + lane] : -INFINITY;
    float m = v;
    #pragma unroll
    for (int off = 1; off < 64; off <<= 1) m = fmaxf(m, __shfl_xor(m, off));
    float ex = (lane < NC) ? expf(v - m) : 0.f;
    float ssum = ex;
    #pragma unroll
    for (int off = 1; off < 64; off <<= 1) ssum += __shfl_xor(ssum, off);
    if (lane < NC) out[(size_t)n * NC + lane] = v - m - logf(ssum);
}

// ---------------- launch ----------------
extern "C" void kernel_launch(void* const* d_in, const int* in_sizes, int n_in,
                              void* d_out, int out_size, void* d_ws, size_t ws_size,
                              hipStream_t stream) {
    const float* x  = (const float*)d_in[0];
    const float* W1 = (const float*)d_in[1];
    const float* W2 = (const float*)d_in[2];
    const int* src  = (const int*)d_in[3];
    const int* dst  = (const int*)d_in[4];
    float* out = (float*)d_out;

    char* w = (char*)d_ws;
    auto alloc = [&](size_t bytes) { char* p = w; w += (bytes + 255) & ~(size_t)255; return p; };
    float* dis   = (float*)alloc((size_t)NN * 4);
    int*   cs    = (int*)  alloc((size_t)NN * 4);
    int*   cd    = (int*)  alloc((size_t)NN * 4);
    int*   curs  = (int*)  alloc((size_t)NN * 4);
    int*   curd  = (int*)  alloc((size_t)NN * 4);
    int*   rps   = (int*)  alloc((size_t)(NN + 1) * 4);
    int*   rpd   = (int*)  alloc((size_t)(NN + 1) * 4);
    int*   bs    = (int*)  alloc(1024 * 4);
    int*   sa    = (int*)  alloc((size_t)NE * 4);
    int*   sb    = (int*)  alloc((size_t)NE * 4);
    int*   pd    = (int*)  alloc((size_t)NE * 4);
    int*   da    = (int*)  alloc((size_t)NE * 4);
    unsigned short* W1h = (unsigned short*)alloc((size_t)HID * FINP * 2);  // 256 KB
    unsigned short* W1l = (unsigned short*)alloc((size_t)HID * FINP * 2);  // 256 KB
    float* hh    = (float*)alloc((size_t)NN * NC * 4);
    float* xc    = (float*)alloc((size_t)NN * NC * 4);
    float* yb    = (float*)alloc((size_t)NN * NC * 4);
    float* S     = (float*)alloc((size_t)NN * NC * 4);
    __half2* xg  = (__half2*)alloc((size_t)NN * PADH2 * 4);
    __half2* xbs = (__half2*)alloc((size_t)NN * PADH2 * 4);
    __half2* zs  = (__half2*)alloc((size_t)NE * NC2 * 4);  // 128 MB
    __half2* zd  = (__half2*)alloc((size_t)NE * NC2 * 4);  // 128 MB
    float* h1    = (float*)zs;  // alias: h1 consumed by k_gemm2 before zs first written

    hipMemsetAsync(cs, 0, (size_t)NN * 4, stream);
    hipMemsetAsync(cd, 0, (size_t)NN * 4, stream);
    hipMemsetAsync(curs, 0, (size_t)NN * 4, stream);
    hipMemsetAsync(curd, 0, (size_t)NN * 4, stream);
    k_hist<<<(NE + 255) / 256, 256, 0, stream>>>(src, dst, cs, cd);
    int nb = (NN + 1023) / 1024;
    k_scan1<<<nb, 1024, 0, stream>>>(cs, rps, bs);
    k_scan2<<<1, 64, 0, stream>>>(bs, nb);
    k_scan3<<<nb, 1024, 0, stream>>>(rps, bs, NE);
    k_scan1<<<nb, 1024, 0, stream>>>(cd, rpd, bs);
    k_scan2<<<1, 64, 0, stream>>>(bs, nb);
    k_scan3<<<nb, 1024, 0, stream>>>(rpd, bs, NE);
    k_dis<<<(NN + 255) / 256, 256, 0, stream>>>(cs, cd, dis);
    k_fillp<<<(NE + 255) / 256, 256, 0, stream>>>(src, dst, rps, rpd, curs, curd, sa, sb, pd, da);

    k_splitW<<<(HID * FINP + 255) / 256, 256, 0, stream>>>(W1, W1h, W1l);
    k_gemm1m<<<(NN + 31) / 32, 256, 0, stream>>>(x, W1h, W1l, h1);
    k_gemm2<<<(NN + 3) / 4, 256, 0, stream>>>(h1, W2, dis, hh, xg);

    hipMemsetAsync(S, 0, (size_t)NN * NC * 4, stream);   // S(z=0)=0 for t=0 ynew
    int zblocks = (int)(((size_t)NE / 2 + 3) / 4);       // 2 edges/wave, 4 waves/block
    for (int t = 0; t < KIT; t++) {
        k_ynew<<<(NN + 3) / 4, 256, 0, stream>>>(rps, rpd, sb, da, dis, (const float2*)hh,
                                                 (const float2*)S, xg, (float2*)yb, xbs);
        k_zup<<<zblocks, 256, 0, stream>>>(sa, sb, pd, xbs, zs, zd, t > 0 ? 1 : 0);
        k_scx<<<(NN + 3) / 4, 256, 0, stream>>>(rps, rpd, zs, zd, (const float2*)yb, dis,
                                                (float2*)S, (float2*)xc, xg);
    }
    k_lsm<<<(NN + 3) / 4, 256, 0, stream>>>(xc, out);
}